// Round 5
// baseline (795.955 us; speedup 1.0000x reference)
//
#include <hip/hip_runtime.h>

// YOLO decode, fused across the 3 scales:
//   x[B,255,S,S] -> out[B, S*S*3, 85]
//   xy  = sigmoid(v)*(1.05*stride) + (g - 0.025)*stride
//   wh  = exp(v)*anchor
//   rest= sigmoid(v)
// Memory-bound transpose via padded LDS. TILE=64: 256B-contiguous reads per
// channel row (full sectors at both row alignments), 64KB contiguous write
// span per block, half the blocks/barriers of TILE=32. 66.3KB LDS -> 2
// blocks/CU @ 512 thr = 16 waves/CU, which R2/R3 showed is BW-sufficient.

#define TILE 64  // hw positions per block

__global__ __launch_bounds__(512) void yolo_fused_kernel(
    const float* __restrict__ x0, const float* __restrict__ x1,
    const float* __restrict__ x2, float* __restrict__ out)
{
    // stride-65 rows: bank = (65*ch+p)%32 = (ch+p)%32 -> conflict-free writes,
    // 2-way (free) on the lane=ch column reads.
    __shared__ float lds[255][TILE + 1];
    __shared__ float gadd[2][TILE];  // (gx-0.025)*stride, (gy-0.025)*stride

    const int t   = blockIdx.x;
    const int b   = blockIdx.y;
    const int tid = threadIdx.x;

    // ---- per-scale parameters (block-uniform selection) ----
    // tiles: ceil(5776/64)=91, ceil(1444/64)=23, ceil(361/64)=6 -> 120
    const float* src; int S, S2, seg_off, tile; float stride;
    float aw0, ah0, aw1, ah1, aw2, ah2; bool vec;
    if (t < 91) {
        src = x0; S = 76; S2 = 5776; seg_off = 0;     stride = 8.0f;  tile = t;
        aw0 = 28.f;  ah0 = 28.f;  aw1 = 46.f;  ah1 = 45.f;  aw2 = 64.f;  ah2 = 66.f;
        vec = true;
    } else if (t < 114) {
        src = x1; S = 38; S2 = 1444; seg_off = 17328; stride = 16.0f; tile = t - 91;
        aw0 = 102.f; ah0 = 74.f;  aw1 = 78.f;  ah1 = 115.f; aw2 = 132.f; ah2 = 113.f;
        vec = true;
    } else {
        src = x2; S = 19; S2 = 361;  seg_off = 21660; stride = 32.0f; tile = t - 114;
        aw0 = 149.f; ah0 = 163.f; aw1 = 174.f; ah1 = 268.f; aw2 = 257.f; ah2 = 176.f;
        vec = false;
    }

    const int hw0    = tile * TILE;
    const int nvalid = min(TILE, S2 - hw0);
    src += (size_t)b * 255 * (size_t)S2;

    // ---- load: 255 channel rows x TILE contiguous hw (float4 when S2%4==0;
    //      vec-scale tails are nvalid%4==0: 5776%64=16, 1444%64=36) ----
    if (vec) {
        const float4* __restrict__ s4 = reinterpret_cast<const float4*>(src + hw0);
        const int rs = S2 >> 2;  // row stride in float4
        for (int idx = tid; idx < 255 * (TILE / 4); idx += 512) {
            int ch = idx >> 4;          // idx / 16
            int q  = idx & 15;          // idx % 16
            int p  = q << 2;
            if (p < nvalid) {
                float4 v = s4[ch * rs + q];
                lds[ch][p]     = v.x;
                lds[ch][p + 1] = v.y;
                lds[ch][p + 2] = v.z;
                lds[ch][p + 3] = v.w;
            }
        }
    } else {
        for (int idx = tid; idx < 255 * TILE; idx += 512) {
            int ch = idx >> 6;          // idx / 64
            int p  = idx & (TILE - 1);  // idx % 64
            if (p < nvalid) lds[ch][p] = src[ch * S2 + hw0 + p];
        }
    }
    if (tid < TILE) {  // grid-term table (64 threads, once per block)
        int hw = hw0 + tid;
        int gy = hw / S;
        int gx = hw - gy * S;
        gadd[0][tid] = ((float)gx - 0.025f) * stride;
        gadd[1][tid] = ((float)gy - 0.025f) * stride;
    }
    __syncthreads();

    // ---- decode + store: thread = (channel, p-half); constants hoisted ----
    const int ch   = tid & 255;   // 0..255 (255 invalid)
    const int half = tid >> 8;    // 0..1 -> p range [32*half, 32*half+32)
    if (ch < 255) {
        int a = ch / 85;
        int c = ch - a * 85;
        bool use_exp = (c == 2) | (c == 3);
        float mulA;
        int addsel;  // 0: +gx term, 1: +gy term, 2: none
        if (c == 0)      { mulA = 1.05f * stride; addsel = 0; }
        else if (c == 1) { mulA = 1.05f * stride; addsel = 1; }
        else if (c == 2) { mulA = (a == 0) ? aw0 : (a == 1) ? aw1 : aw2; addsel = 2; }
        else if (c == 3) { mulA = (a == 0) ? ah0 : (a == 1) ? ah1 : ah2; addsel = 2; }
        else             { mulA = 1.0f; addsel = 2; }

        float* __restrict__ dst =
            out + ((size_t)b * 22743 + (size_t)seg_off) * 85 + (size_t)hw0 * 255 + ch;

        const int p0 = half * 32;
        const int p1 = min(p0 + 32, nvalid);
        #pragma unroll 4
        for (int p = p0; p < p1; ++p) {
            float v = lds[ch][p];
            float e = __expf(use_exp ? v : -v);                       // v_exp_f32
            float s = use_exp ? e : __builtin_amdgcn_rcpf(1.0f + e);  // v_rcp_f32
            float add = (addsel == 0) ? gadd[0][p]
                      : (addsel == 1) ? gadd[1][p] : 0.0f;
            dst[(size_t)p * 255] = s * mulA + add;
        }
    }
}

extern "C" void kernel_launch(void* const* d_in, const int* in_sizes, int n_in,
                              void* d_out, int out_size, void* d_ws, size_t ws_size,
                              hipStream_t stream) {
    const float* x0 = (const float*)d_in[0];  // [64,255,76,76]
    const float* x1 = (const float*)d_in[1];  // [64,255,38,38]
    const float* x2 = (const float*)d_in[2];  // [64,255,19,19]
    float* out = (float*)d_out;               // [64, 22743, 85]

    yolo_fused_kernel<<<dim3(120, 64), dim3(512), 0, stream>>>(x0, x1, x2, out);
}

// Round 6
// 778.942 us; speedup vs baseline: 1.0218x; 1.0218x over previous
//
#include <hip/hip_runtime.h>

// YOLO decode, fused across the 3 scales:
//   x[B,255,S,S] -> out[B, S*S*3, 85]
//   xy  = sigmoid(v)*(1.05*stride) + (g - 0.025)*stride
//   wh  = exp(v)*anchor
//   rest= sigmoid(v)
// Memory-bound transpose via padded LDS. TILE=32 / 512 threads was the
// measured-best config (R3: 782.6 us wall): 33.8KB LDS -> 4 blocks/CU,
// 32 waves/CU. TILE=64 (R5) and 256-thread (R2) variants were null or
// slightly worse; decode is branchless with native exp/rcp so the store
// phase is ~6 VALU ops/element.

#define TILE 32  // hw positions per block

__global__ __launch_bounds__(512) void yolo_fused_kernel(
    const float* __restrict__ x0, const float* __restrict__ x1,
    const float* __restrict__ x2, float* __restrict__ out)
{
    // stride-33 rows: bank = (33*ch+p)%32 = (ch+p)%32 -> conflict-free on the
    // row-contig writes and <=2-way (free) on the lane=ch column reads.
    __shared__ float lds[255][TILE + 1];
    __shared__ float gadd[2][TILE];  // (gx-0.025)*stride, (gy-0.025)*stride

    const int t   = blockIdx.x;
    const int b   = blockIdx.y;
    const int tid = threadIdx.x;

    // ---- per-scale parameters (block-uniform selection) ----
    const float* src; int S, S2, seg_off, tile; float stride;
    float aw0, ah0, aw1, ah1, aw2, ah2; bool vec;
    if (t < 181) {
        src = x0; S = 76; S2 = 5776; seg_off = 0;     stride = 8.0f;  tile = t;
        aw0 = 28.f;  ah0 = 28.f;  aw1 = 46.f;  ah1 = 45.f;  aw2 = 64.f;  ah2 = 66.f;
        vec = true;
    } else if (t < 227) {
        src = x1; S = 38; S2 = 1444; seg_off = 17328; stride = 16.0f; tile = t - 181;
        aw0 = 102.f; ah0 = 74.f;  aw1 = 78.f;  ah1 = 115.f; aw2 = 132.f; ah2 = 113.f;
        vec = true;
    } else {
        src = x2; S = 19; S2 = 361;  seg_off = 21660; stride = 32.0f; tile = t - 227;
        aw0 = 149.f; ah0 = 163.f; aw1 = 174.f; ah1 = 268.f; aw2 = 257.f; ah2 = 176.f;
        vec = false;
    }

    const int hw0    = tile * TILE;
    const int nvalid = min(TILE, S2 - hw0);
    src += (size_t)b * 255 * (size_t)S2;

    // ---- load: 255 channel rows x TILE contiguous hw (float4 when S2%4==0) ----
    if (vec) {
        const float4* __restrict__ s4 = reinterpret_cast<const float4*>(src + hw0);
        const int rs = S2 >> 2;  // row stride in float4
        for (int idx = tid; idx < 255 * (TILE / 4); idx += 512) {
            int ch = idx >> 3;          // idx / 8
            int q  = idx & 7;           // idx % 8
            int p  = q << 2;
            if (p < nvalid) {
                float4 v = s4[ch * rs + q];
                lds[ch][p]     = v.x;
                lds[ch][p + 1] = v.y;
                lds[ch][p + 2] = v.z;
                lds[ch][p + 3] = v.w;
            }
        }
    } else {
        for (int idx = tid; idx < 255 * TILE; idx += 512) {
            int ch = idx >> 5;
            int p  = idx & (TILE - 1);
            if (p < nvalid) lds[ch][p] = src[ch * S2 + hw0 + p];
        }
    }
    if (tid < TILE) {  // grid-term table (32 threads, once per block)
        int hw = hw0 + tid;
        int gy = hw / S;
        int gx = hw - gy * S;
        gadd[0][tid] = ((float)gx - 0.025f) * stride;
        gadd[1][tid] = ((float)gy - 0.025f) * stride;
    }
    __syncthreads();

    // ---- decode + store: thread = (channel, p-half); constants hoisted ----
    const int ch   = tid & 255;   // 0..255 (255 invalid)
    const int half = tid >> 8;    // 0..1 -> p range [16*half, 16*half+16)
    if (ch < 255) {
        int a = ch / 85;
        int c = ch - a * 85;
        bool use_exp = (c == 2) | (c == 3);
        float mulA;
        int addsel;  // 0: +gx term, 1: +gy term, 2: none
        if (c == 0)      { mulA = 1.05f * stride; addsel = 0; }
        else if (c == 1) { mulA = 1.05f * stride; addsel = 1; }
        else if (c == 2) { mulA = (a == 0) ? aw0 : (a == 1) ? aw1 : aw2; addsel = 2; }
        else if (c == 3) { mulA = (a == 0) ? ah0 : (a == 1) ? ah1 : ah2; addsel = 2; }
        else             { mulA = 1.0f; addsel = 2; }

        float* __restrict__ dst =
            out + ((size_t)b * 22743 + (size_t)seg_off) * 85 + (size_t)hw0 * 255 + ch;

        const int p0 = half * 16;
        const int p1 = min(p0 + 16, nvalid);
        #pragma unroll 4
        for (int p = p0; p < p1; ++p) {
            float v = lds[ch][p];
            float e = __expf(use_exp ? v : -v);                       // v_exp_f32
            float s = use_exp ? e : __builtin_amdgcn_rcpf(1.0f + e);  // v_rcp_f32
            float add = (addsel == 0) ? gadd[0][p]
                      : (addsel == 1) ? gadd[1][p] : 0.0f;
            dst[(size_t)p * 255] = s * mulA + add;
        }
    }
}

extern "C" void kernel_launch(void* const* d_in, const int* in_sizes, int n_in,
                              void* d_out, int out_size, void* d_ws, size_t ws_size,
                              hipStream_t stream) {
    const float* x0 = (const float*)d_in[0];  // [64,255,76,76]
    const float* x1 = (const float*)d_in[1];  // [64,255,38,38]
    const float* x2 = (const float*)d_in[2];  // [64,255,19,19]
    float* out = (float*)d_out;               // [64, 22743, 85]

    // tiles: ceil(5776/32)=181, ceil(1444/32)=46, ceil(361/32)=12 -> 239
    yolo_fused_kernel<<<dim3(239, 64), dim3(512), 0, stream>>>(x0, x1, x2, out);
}